// Round 10
// baseline (1099.837 us; speedup 1.0000x reference)
//
#include <hip/hip_runtime.h>

typedef __attribute__((ext_vector_type(8))) short bf16x8;
typedef __attribute__((ext_vector_type(4))) float f32x4;

#define NB_ROWS 65536
#define D_EMBED 256
#define D_HID   256
#define N_EXP   8
#define D_RHID  128
#define D_IN    640

#define KSTR 72   // K-tile LDS stride: 144B rows, 16B aligned, 8-bank spread

static __device__ __forceinline__ ushort f2bf(float f) {
  union { float f; unsigned u; } v; v.f = f;
  unsigned r = v.u + 0x7fffu + ((v.u >> 16) & 1u);
  return (ushort)(r >> 16);
}
static __device__ __forceinline__ float bf2f(ushort h) {
  union { unsigned u; float f; } v; v.u = ((unsigned)h) << 16;
  return v.f;
}
static __device__ __forceinline__ float silu_f(float x) {
  return x / (1.0f + __expf(-x));
}

// swizzled offset for [rows][256] bf16 LDS tile read as bf16x8 along K:
// 16B-slot index XORed with (row&7); 16 consecutive rows -> 2-way alias (free, m136)
static __device__ __forceinline__ int hswz(int r, int c) {
  return r * 256 + ((((c) >> 3) ^ (r & 7)) << 3) + ((c) & 7);
}

// ---------------- weight prep: [nm][R][C] f32 -> [nm][C][R] bf16 ----------------
__global__ void prep_transpose(const float* __restrict__ src, ushort* __restrict__ dst,
                               int R, int C, int total) {
  int idx = blockIdx.x * 256 + threadIdx.x;
  if (idx >= total) return;
  int rc = R * C;
  int m = idx / rc;
  int rem = idx - m * rc;
  int r = rem / C;
  int c = rem - r * C;
  dst[m * rc + c * R + r] = f2bf(src[idx]);
}

// ---- combined load+write staging (short register lifetime: no spill) ----
// [64 rows][64 cols] bf16 K-tile, NT=512: 1 chunk of 16B per thread
static __device__ __forceinline__ void stageA64_512(const ushort* __restrict__ src, int ld,
                                                    int kt, ushort* dst, int tid) {
  int f = tid * 16;
  int r = f >> 7, ce = (f & 127) >> 1;
  uint4 v = *(const uint4*)&src[(size_t)r * ld + kt + ce];
  *(uint4*)&dst[r * KSTR + ce] = v;
}
// [256 rows][64 cols] bf16 K-tile, NT=512: 4 chunks of 16B per thread
static __device__ __forceinline__ void stageB256_512(const ushort* __restrict__ src, int ld,
                                                     int kt, ushort* dst, int tid) {
  uint4 v[4];
  #pragma unroll
  for (int c = 0; c < 4; ++c) {
    int f = c * 8192 + tid * 16;
    int r = f >> 7, ce = (f & 127) >> 1;
    v[c] = *(const uint4*)&src[(size_t)r * ld + kt + ce];
  }
  #pragma unroll
  for (int c = 0; c < 4; ++c) {
    int f = c * 8192 + tid * 16;
    int r = f >> 7, ce = (f & 127) >> 1;
    *(uint4*)&dst[r * KSTR + ce] = v[c];
  }
}
// [128 rows][64 cols] bf16 K-tile, NT=256 (router)
static __device__ __forceinline__ void stageA128_256(const ushort* __restrict__ src, int ld,
                                                     int kt, ushort* dst, int tid) {
  uint4 v[4];
  #pragma unroll
  for (int c = 0; c < 4; ++c) {
    int f = c * 4096 + tid * 16;
    int r = f >> 7, ce = (f & 127) >> 1;
    v[c] = *(const uint4*)&src[(size_t)r * ld + kt + ce];
  }
  #pragma unroll
  for (int c = 0; c < 4; ++c) {
    int f = c * 4096 + tid * 16;
    int r = f >> 7, ce = (f & 127) >> 1;
    *(uint4*)&dst[r * KSTR + ce] = v[c];
  }
}

// ---------------- time embedding MLP + build x = [z | te | cond] (bf16) ----------------
__global__ __launch_bounds__(512) void time_x_kernel(
    const float* __restrict__ zt, const float* __restrict__ tin,
    const float* __restrict__ cond,
    const ushort* __restrict__ tw1t, const ushort* __restrict__ tw2t,
    const float* __restrict__ tb1, const float* __restrict__ tb2,
    ushort* __restrict__ x) {
  __shared__ __align__(16) ushort sE[128 * 136];
  __shared__ float sFreq[64];
  __shared__ float sB1[128];
  __shared__ float sB2[128];

  const int tid = threadIdx.x;
  const int row0 = blockIdx.x * 128;

  for (int ch = tid; ch < 128 * 64; ch += 512) {
    int r = ch >> 6;
    int c4 = (ch & 63) << 2;
    size_t grow = (size_t)(row0 + r);
    float4 zv = *(const float4*)&zt[grow * 256 + c4];
    ushort4 o; o.x = f2bf(zv.x); o.y = f2bf(zv.y); o.z = f2bf(zv.z); o.w = f2bf(zv.w);
    *(ushort4*)&x[grow * 640 + c4] = o;
    float4 cv = *(const float4*)&cond[grow * 256 + c4];
    ushort4 o2; o2.x = f2bf(cv.x); o2.y = f2bf(cv.y); o2.z = f2bf(cv.z); o2.w = f2bf(cv.w);
    *(ushort4*)&x[grow * 640 + 384 + c4] = o2;
  }

  if (tid < 64) sFreq[tid] = __expf((float)tid * (-9.210340371976184f / 63.0f));
  if (tid < 128) { sB1[tid] = tb1[tid]; sB2[tid] = tb2[tid]; }
  __syncthreads();

  {
    int r = tid >> 2;
    int qd = tid & 3;
    float tv = tin[row0 + r];
    int half = qd >> 1;
    int cbase = (qd & 1) * 32;
    ushort* er = &sE[r * 136 + half * 64 + cbase];
    #pragma unroll
    for (int c = 0; c < 32; ++c) {
      float a = tv * sFreq[cbase + c];
      float v = half ? __cosf(a) : __sinf(a);
      er[c] = f2bf(v);
    }
  }
  __syncthreads();

  const int l = tid & 63;
  const int w = tid >> 6;   // 8 waves: 4(M) x 2(N) of 32x64
  const int wm = w >> 1;
  const int wn = w & 1;
  const int lr = l & 15;
  const int lk = (l >> 4) * 8;
  const int q4 = (l >> 4) * 4;

  f32x4 acc[2][4] = {};
  #pragma unroll
  for (int kk = 0; kk < 4; ++kk) {
    int kb = kk * 32 + lk;
    bf16x8 av[2], bv[4];
    #pragma unroll
    for (int mf = 0; mf < 2; ++mf)
      av[mf] = *(const bf16x8*)&sE[(wm * 32 + mf * 16 + lr) * 136 + kb];
    #pragma unroll
    for (int nf = 0; nf < 4; ++nf)
      bv[nf] = *(const bf16x8*)&tw1t[(size_t)(wn * 64 + nf * 16 + lr) * 128 + kb];
    #pragma unroll
    for (int mf = 0; mf < 2; ++mf)
      #pragma unroll
      for (int nf = 0; nf < 4; ++nf)
        acc[mf][nf] = __builtin_amdgcn_mfma_f32_16x16x32_bf16(av[mf], bv[nf], acc[mf][nf], 0, 0, 0);
  }
  __syncthreads();
  #pragma unroll
  for (int mf = 0; mf < 2; ++mf)
    #pragma unroll
    for (int nf = 0; nf < 4; ++nf) {
      int cc = wn * 64 + nf * 16 + lr;
      #pragma unroll
      for (int rg = 0; rg < 4; ++rg) {
        int rr = wm * 32 + mf * 16 + q4 + rg;
        sE[rr * 136 + cc] = f2bf(silu_f(acc[mf][nf][rg] + sB1[cc]));
      }
    }
  __syncthreads();

  f32x4 acc2[2][4] = {};
  #pragma unroll
  for (int kk = 0; kk < 4; ++kk) {
    int kb = kk * 32 + lk;
    bf16x8 av[2], bv[4];
    #pragma unroll
    for (int mf = 0; mf < 2; ++mf)
      av[mf] = *(const bf16x8*)&sE[(wm * 32 + mf * 16 + lr) * 136 + kb];
    #pragma unroll
    for (int nf = 0; nf < 4; ++nf)
      bv[nf] = *(const bf16x8*)&tw2t[(size_t)(wn * 64 + nf * 16 + lr) * 128 + kb];
    #pragma unroll
    for (int mf = 0; mf < 2; ++mf)
      #pragma unroll
      for (int nf = 0; nf < 4; ++nf)
        acc2[mf][nf] = __builtin_amdgcn_mfma_f32_16x16x32_bf16(av[mf], bv[nf], acc2[mf][nf], 0, 0, 0);
  }
  #pragma unroll
  for (int mf = 0; mf < 2; ++mf)
    #pragma unroll
    for (int nf = 0; nf < 4; ++nf) {
      int cc = wn * 64 + nf * 16 + lr;
      #pragma unroll
      for (int rg = 0; rg < 4; ++rg) {
        int rr = wm * 32 + mf * 16 + q4 + rg;
        x[(size_t)(row0 + rr) * 640 + 256 + cc] = f2bf(acc2[mf][nf][rg] + sB2[cc]);
      }
    }
}

// ---------------- fused router ----------------
__global__ __launch_bounds__(256) void router_kernel(
    const ushort* __restrict__ xb, const ushort* __restrict__ rw1t,
    const float* __restrict__ rb1, const float* __restrict__ rW2,
    const float* __restrict__ rb2, float* __restrict__ gatef,
    float* __restrict__ gateo) {
  __shared__ __align__(16) ushort smA[128 * KSTR];
  __shared__ __align__(16) ushort smB[128 * KSTR];
  __shared__ __align__(16) ushort rhbuf[128 * 136];
  __shared__ float sW2[128 * 8];

  const int tid = threadIdx.x;
  const int row0 = blockIdx.x * 128;
  for (int i = tid; i < 1024; i += 256) sW2[i] = rW2[i];

  const int l = tid & 63;
  const int w = tid >> 6;     // 4 waves: 2x2 of 64x64
  const int wm = w >> 1, wn = w & 1;
  const int lr = l & 15, lk = (l >> 4) * 8, q4 = (l >> 4) * 4;
  const ushort* xrow = xb + (size_t)row0 * 640;

  f32x4 acc[4][4] = {};
  for (int kt = 0; kt < 640; kt += 64) {
    stageA128_256(xrow, 640, kt, smA, tid);
    stageA128_256(rw1t, 640, kt, smB, tid);
    __syncthreads();
    #pragma unroll
    for (int kk = 0; kk < 2; ++kk) {
      int kb = kk * 32 + lk;
      bf16x8 av[4], bv[4];
      #pragma unroll
      for (int mf = 0; mf < 4; ++mf)
        av[mf] = *(const bf16x8*)&smA[(wm * 64 + mf * 16 + lr) * KSTR + kb];
      #pragma unroll
      for (int nf = 0; nf < 4; ++nf)
        bv[nf] = *(const bf16x8*)&smB[(wn * 64 + nf * 16 + lr) * KSTR + kb];
      #pragma unroll
      for (int mf = 0; mf < 4; ++mf)
        #pragma unroll
        for (int nf = 0; nf < 4; ++nf)
          acc[mf][nf] = __builtin_amdgcn_mfma_f32_16x16x32_bf16(av[mf], bv[nf], acc[mf][nf], 0, 0, 0);
    }
    __syncthreads();
  }
  #pragma unroll
  for (int nf = 0; nf < 4; ++nf) {
    int cc = wn * 64 + nf * 16 + lr;
    float b1v = rb1[cc];
    #pragma unroll
    for (int mf = 0; mf < 4; ++mf)
      #pragma unroll
      for (int rg = 0; rg < 4; ++rg) {
        int rr = wm * 64 + mf * 16 + q4 + rg;
        rhbuf[rr * 136 + cc] = f2bf(silu_f(acc[mf][nf][rg] + b1v));
      }
  }
  __syncthreads();

  if (tid < 128) {
    float a[8];
    #pragma unroll
    for (int e = 0; e < 8; ++e) a[e] = rb2[e];
    #pragma unroll
    for (int i8 = 0; i8 < 16; ++i8) {
      bf16x8 hv = *(const bf16x8*)&rhbuf[tid * 136 + i8 * 8];
      #pragma unroll
      for (int j = 0; j < 8; ++j) {
        float h = bf2f((ushort)hv[j]);
        const float* wrow = &sW2[(i8 * 8 + j) * 8];
        #pragma unroll
        for (int e = 0; e < 8; ++e) a[e] += h * wrow[e];
      }
    }
    float mx = a[0];
    #pragma unroll
    for (int e = 1; e < 8; ++e) mx = fmaxf(mx, a[e]);
    float s = 0.f, ex[8];
    #pragma unroll
    for (int e = 0; e < 8; ++e) { ex[e] = __expf(a[e] - mx); s += ex[e]; }
    float inv = 1.f / s;
    size_t b = (size_t)(row0 + tid);
    #pragma unroll
    for (int e = 0; e < 8; ++e) {
      float g = ex[e] * inv;
      gatef[b * 8 + e] = g;
      gateo[b * 8 + e] = g;     // FLOAT32 output
    }
  }
}

// ---------------- fused MoE: BM=64, 80KB LDS -> 2 blocks/CU for latency overlap ----------------
__global__ __launch_bounds__(512, 4) void moe_fused_kernel(
    const ushort* __restrict__ xb, const ushort* __restrict__ w1t,
    const ushort* __restrict__ w2t, const ushort* __restrict__ w3t,
    const float* __restrict__ eb1, const float* __restrict__ eb2,
    const float* __restrict__ eb3, const float* __restrict__ gatef,
    float* __restrict__ velout) {
  __shared__ __align__(16) ushort smA[64 * KSTR];     //  9.2 KB: x K-tile
  __shared__ __align__(16) ushort smB[256 * KSTR];    // 36.9 KB: weight K-tile (N=256)
  __shared__ __align__(16) ushort hbuf[64 * 256];     // 32.8 KB: h tile, XOR-swizzled
  __shared__ float sGate[64 * 8];                     //  2 KB
  // total 80,896 B <= 81,920 B -> 2 blocks/CU

  const int tid = threadIdx.x;
  const int row0 = blockIdx.x * 64;
  const int l = tid & 63;
  const int w = tid >> 6;     // 8 waves: 2(M) x 4(N), wave tile 32x64
  const int wm = w >> 2;
  const int wn = w & 3;
  const int lr = l & 15;
  const int lk = (l >> 4) * 8;
  const int q4 = (l >> 4) * 4;

  for (int i = tid; i < 512; i += 512) sGate[i] = gatef[(size_t)row0 * 8 + i];

  const ushort* xrow = xb + (size_t)row0 * 640;
  f32x4 vacc[2][4] = {};
  __syncthreads();

  for (int e = 0; e < 8; ++e) {
    const ushort* W1 = w1t + (size_t)e * (256 * 640);
    const ushort* W2 = w2t + (size_t)e * (256 * 256);
    const ushort* W3 = w3t + (size_t)e * (256 * 256);

    // ---- stage 1: h1 = silu(x @ W1 + b1), K=640 ----
    f32x4 acc[2][4] = {};
    for (int kt = 0; kt < 640; kt += 64) {
      stageA64_512(xrow, 640, kt, smA, tid);
      stageB256_512(W1, 640, kt, smB, tid);
      __syncthreads();
      #pragma unroll
      for (int kk = 0; kk < 2; ++kk) {
        int kb = kk * 32 + lk;
        bf16x8 av[2], bv[4];
        #pragma unroll
        for (int mf = 0; mf < 2; ++mf)
          av[mf] = *(const bf16x8*)&smA[(wm * 32 + mf * 16 + lr) * KSTR + kb];
        #pragma unroll
        for (int nf = 0; nf < 4; ++nf)
          bv[nf] = *(const bf16x8*)&smB[(wn * 64 + nf * 16 + lr) * KSTR + kb];
        #pragma unroll
        for (int mf = 0; mf < 2; ++mf)
          #pragma unroll
          for (int nf = 0; nf < 4; ++nf)
            acc[mf][nf] = __builtin_amdgcn_mfma_f32_16x16x32_bf16(av[mf], bv[nf], acc[mf][nf], 0, 0, 0);
      }
      __syncthreads();
    }
    // epilogue 1 -> hbuf (swizzled)
    #pragma unroll
    for (int nf = 0; nf < 4; ++nf) {
      int cc = wn * 64 + nf * 16 + lr;
      float b1v = eb1[e * 256 + cc];
      #pragma unroll
      for (int mf = 0; mf < 2; ++mf)
        #pragma unroll
        for (int rg = 0; rg < 4; ++rg) {
          int rr = wm * 32 + mf * 16 + q4 + rg;
          hbuf[hswz(rr, cc)] = f2bf(silu_f(acc[mf][nf][rg] + b1v));
        }
    }
    __syncthreads();

    // ---- stage 2: h2g = gate * silu(h1 @ W2 + b2), K=256 ----
    #pragma unroll
    for (int mf = 0; mf < 2; ++mf)
      #pragma unroll
      for (int nf = 0; nf < 4; ++nf)
        acc[mf][nf] = (f32x4){0.f, 0.f, 0.f, 0.f};
    for (int kt = 0; kt < 256; kt += 64) {
      stageB256_512(W2, 256, kt, smB, tid);
      __syncthreads();
      #pragma unroll
      for (int kk = 0; kk < 2; ++kk) {
        int kbl = kk * 32 + lk;
        int kbh = kt + kbl;
        bf16x8 av[2], bv[4];
        #pragma unroll
        for (int mf = 0; mf < 2; ++mf)
          av[mf] = *(const bf16x8*)&hbuf[hswz(wm * 32 + mf * 16 + lr, kbh)];
        #pragma unroll
        for (int nf = 0; nf < 4; ++nf)
          bv[nf] = *(const bf16x8*)&smB[(wn * 64 + nf * 16 + lr) * KSTR + kbl];
        #pragma unroll
        for (int mf = 0; mf < 2; ++mf)
          #pragma unroll
          for (int nf = 0; nf < 4; ++nf)
            acc[mf][nf] = __builtin_amdgcn_mfma_f32_16x16x32_bf16(av[mf], bv[nf], acc[mf][nf], 0, 0, 0);
      }
      __syncthreads();
    }
    // epilogue 2 -> hbuf (gate folded in; reads drained by trailing barrier)
    #pragma unroll
    for (int nf = 0; nf < 4; ++nf) {
      int cc = wn * 64 + nf * 16 + lr;
      float b2v = eb2[e * 256 + cc];
      #pragma unroll
      for (int mf = 0; mf < 2; ++mf)
        #pragma unroll
        for (int rg = 0; rg < 4; ++rg) {
          int rr = wm * 32 + mf * 16 + q4 + rg;
          float gv = sGate[rr * 8 + e];
          hbuf[hswz(rr, cc)] = f2bf(silu_f(acc[mf][nf][rg] + b2v) * gv);
        }
    }
    __syncthreads();

    // ---- stage 3: vacc += h2g @ W3, K=256 ----
    for (int kt = 0; kt < 256; kt += 64) {
      stageB256_512(W3, 256, kt, smB, tid);
      __syncthreads();
      #pragma unroll
      for (int kk = 0; kk < 2; ++kk) {
        int kbl = kk * 32 + lk;
        int kbh = kt + kbl;
        bf16x8 av[2], bv[4];
        #pragma unroll
        for (int mf = 0; mf < 2; ++mf)
          av[mf] = *(const bf16x8*)&hbuf[hswz(wm * 32 + mf * 16 + lr, kbh)];
        #pragma unroll
        for (int nf = 0; nf < 4; ++nf)
          bv[nf] = *(const bf16x8*)&smB[(wn * 64 + nf * 16 + lr) * KSTR + kbl];
        #pragma unroll
        for (int mf = 0; mf < 2; ++mf)
          #pragma unroll
          for (int nf = 0; nf < 4; ++nf)
            vacc[mf][nf] = __builtin_amdgcn_mfma_f32_16x16x32_bf16(av[mf], bv[nf], vacc[mf][nf], 0, 0, 0);
      }
      __syncthreads();
    }
  }

  // stage eb3 into smA's space (smB/smA free now), then final epilogue (FLOAT32 out)
  float* eL = (float*)smA;   // 8 KB <= 9.2 KB
  for (int i = tid; i < 2048; i += 512) eL[i] = eb3[i];
  __syncthreads();
  #pragma unroll
  for (int mf = 0; mf < 2; ++mf)
    #pragma unroll
    for (int rg = 0; rg < 4; ++rg) {
      int rr = wm * 32 + mf * 16 + q4 + rg;
      const float* gp = &sGate[rr * 8];
      #pragma unroll
      for (int nf = 0; nf < 4; ++nf) {
        int cc = wn * 64 + nf * 16 + lr;
        float bsum = 0.f;
        #pragma unroll
        for (int ee = 0; ee < 8; ++ee) bsum += gp[ee] * eL[ee * 256 + cc];
        velout[(size_t)(row0 + rr) * D_EMBED + cc] = vacc[mf][nf][rg] + bsum;
      }
    }
}

extern "C" void kernel_launch(void* const* d_in, const int* in_sizes, int n_in,
                              void* d_out, int out_size, void* d_ws, size_t ws_size,
                              hipStream_t stream) {
  const float* zt   = (const float*)d_in[0];
  const float* tin  = (const float*)d_in[1];
  const float* cond = (const float*)d_in[2];
  const float* tW1  = (const float*)d_in[3];
  const float* tb1  = (const float*)d_in[4];
  const float* tW2  = (const float*)d_in[5];
  const float* tb2  = (const float*)d_in[6];
  const float* eW1  = (const float*)d_in[7];
  const float* eb1  = (const float*)d_in[8];
  const float* eW2  = (const float*)d_in[9];
  const float* eb2  = (const float*)d_in[10];
  const float* eW3  = (const float*)d_in[11];
  const float* eb3  = (const float*)d_in[12];
  const float* rW1  = (const float*)d_in[13];
  const float* rb1  = (const float*)d_in[14];
  const float* rW2  = (const float*)d_in[15];
  const float* rb2  = (const float*)d_in[16];

  char* wp = (char*)d_ws;
  ushort* xb    = (ushort*)wp; wp += (size_t)NB_ROWS * D_IN * 2;        // 80 MiB
  float*  gatef = (float*)wp;  wp += (size_t)NB_ROWS * 8 * 4;           // 2 MiB
  ushort* w1t   = (ushort*)wp; wp += (size_t)N_EXP * D_HID * D_IN * 2;
  ushort* w2t   = (ushort*)wp; wp += (size_t)N_EXP * D_HID * D_HID * 2;
  ushort* w3t   = (ushort*)wp; wp += (size_t)N_EXP * D_HID * D_EMBED * 2;
  ushort* rw1t  = (ushort*)wp; wp += (size_t)D_RHID * D_IN * 2;
  ushort* tw1t  = (ushort*)wp; wp += (size_t)128 * 128 * 2;
  ushort* tw2t  = (ushort*)wp; wp += (size_t)128 * 128 * 2;
  // total ~87 MiB (proven safe)

  // FLOAT32 outputs (reference returns jnp.float32)
  float* velout  = (float*)d_out;
  float* gateout = velout + (size_t)NB_ROWS * D_EMBED;

  // weight prep
  {
    int tot;
    tot = 128 * 128;
    prep_transpose<<<(tot + 255) / 256, 256, 0, stream>>>(tW1, tw1t, 128, 128, tot);
    prep_transpose<<<(tot + 255) / 256, 256, 0, stream>>>(tW2, tw2t, 128, 128, tot);
    tot = D_IN * D_RHID;
    prep_transpose<<<(tot + 255) / 256, 256, 0, stream>>>(rW1, rw1t, D_IN, D_RHID, tot);
    tot = N_EXP * D_IN * D_HID;
    prep_transpose<<<(tot + 255) / 256, 256, 0, stream>>>(eW1, w1t, D_IN, D_HID, tot);
    tot = N_EXP * D_HID * D_HID;
    prep_transpose<<<(tot + 255) / 256, 256, 0, stream>>>(eW2, w2t, D_HID, D_HID, tot);
    tot = N_EXP * D_HID * D_EMBED;
    prep_transpose<<<(tot + 255) / 256, 256, 0, stream>>>(eW3, w3t, D_HID, D_EMBED, tot);
  }

  time_x_kernel<<<512, 512, 0, stream>>>(zt, tin, cond, tw1t, tw2t, tb1, tb2, xb);
  router_kernel<<<512, 256, 0, stream>>>(xb, rw1t, rb1, rW2, rb2, gatef, gateout);
  moe_fused_kernel<<<1024, 512, 0, stream>>>(xb, w1t, w2t, w3t, eb1, eb2, eb3, gatef, velout);
}

// Round 11
// 1031.337 us; speedup vs baseline: 1.0664x; 1.0664x over previous
//
#include <hip/hip_runtime.h>

typedef __attribute__((ext_vector_type(8))) short bf16x8;
typedef __attribute__((ext_vector_type(4))) float f32x4;

#define NB_ROWS 65536
#define D_EMBED 256
#define D_HID   256
#define N_EXP   8
#define D_RHID  128
#define D_IN    640

// LDS strides (elements): K-tiles 64 -> 72 (144B rows, 16B aligned, 8-bank spread)
// h-tile 256 -> 264 (528B rows, 16B aligned)
#define KSTR 72
#define HSTR 264

static __device__ __forceinline__ ushort f2bf(float f) {
  union { float f; unsigned u; } v; v.f = f;
  unsigned r = v.u + 0x7fffu + ((v.u >> 16) & 1u);
  return (ushort)(r >> 16);
}
static __device__ __forceinline__ float bf2f(ushort h) {
  union { unsigned u; float f; } v; v.u = ((unsigned)h) << 16;
  return v.f;
}
static __device__ __forceinline__ float silu_f(float x) {
  return x / (1.0f + __expf(-x));
}

// ---------------- weight prep: [nm][R][C] f32 -> [nm][C][R] bf16 ----------------
__global__ void prep_transpose(const float* __restrict__ src, ushort* __restrict__ dst,
                               int R, int C, int total) {
  int idx = blockIdx.x * 256 + threadIdx.x;
  if (idx >= total) return;
  int rc = R * C;
  int m = idx / rc;
  int rem = idx - m * rc;
  int r = rem / C;
  int c = rem - r * C;
  dst[m * rc + c * R + r] = f2bf(src[idx]);
}

// ---- T14 split staging: load-to-regs (issue early) / write-to-LDS (late) ----
// [128 rows][64 cols] bf16 K-tile, NT=512: 2 chunks of 16B per thread
static __device__ __forceinline__ void loadA128_512(const ushort* __restrict__ src, int ld,
                                                    int kt, int tid, uint4* v) {
  #pragma unroll
  for (int c = 0; c < 2; ++c) {
    int f = c * 8192 + tid * 16;
    int r = f >> 7, ce = (f & 127) >> 1;
    v[c] = *(const uint4*)&src[(size_t)r * ld + kt + ce];
  }
}
static __device__ __forceinline__ void writeA128_512(ushort* dst, int tid, const uint4* v) {
  #pragma unroll
  for (int c = 0; c < 2; ++c) {
    int f = c * 8192 + tid * 16;
    int r = f >> 7, ce = (f & 127) >> 1;
    *(uint4*)&dst[r * KSTR + ce] = v[c];
  }
}
// [256 rows][64 cols] bf16 K-tile, NT=512: 4 chunks of 16B per thread
static __device__ __forceinline__ void loadB256_512(const ushort* __restrict__ src, int ld,
                                                    int kt, int tid, uint4* v) {
  #pragma unroll
  for (int c = 0; c < 4; ++c) {
    int f = c * 8192 + tid * 16;
    int r = f >> 7, ce = (f & 127) >> 1;
    v[c] = *(const uint4*)&src[(size_t)r * ld + kt + ce];
  }
}
static __device__ __forceinline__ void writeB256_512(ushort* dst, int tid, const uint4* v) {
  #pragma unroll
  for (int c = 0; c < 4; ++c) {
    int f = c * 8192 + tid * 16;
    int r = f >> 7, ce = (f & 127) >> 1;
    *(uint4*)&dst[r * KSTR + ce] = v[c];
  }
}
// [128 rows][64 cols] bf16 K-tile, NT=256 (router, 2-phase)
static __device__ __forceinline__ void stageA128_256(const ushort* __restrict__ src, int ld,
                                                     int kt, ushort* dst, int tid) {
  uint4 v[4];
  #pragma unroll
  for (int c = 0; c < 4; ++c) {
    int f = c * 4096 + tid * 16;
    int r = f >> 7, ce = (f & 127) >> 1;
    v[c] = *(const uint4*)&src[(size_t)r * ld + kt + ce];
  }
  #pragma unroll
  for (int c = 0; c < 4; ++c) {
    int f = c * 4096 + tid * 16;
    int r = f >> 7, ce = (f & 127) >> 1;
    *(uint4*)&dst[r * KSTR + ce] = v[c];
  }
}

// ---------------- time embedding MLP + build x = [z | te | cond] (bf16) ----------------
__global__ __launch_bounds__(512) void time_x_kernel(
    const float* __restrict__ zt, const float* __restrict__ tin,
    const float* __restrict__ cond,
    const ushort* __restrict__ tw1t, const ushort* __restrict__ tw2t,
    const float* __restrict__ tb1, const float* __restrict__ tb2,
    ushort* __restrict__ x) {
  __shared__ __align__(16) ushort sE[128 * 136];
  __shared__ float sFreq[64];
  __shared__ float sB1[128];
  __shared__ float sB2[128];

  const int tid = threadIdx.x;
  const int row0 = blockIdx.x * 128;

  for (int ch = tid; ch < 128 * 64; ch += 512) {
    int r = ch >> 6;
    int c4 = (ch & 63) << 2;
    size_t grow = (size_t)(row0 + r);
    float4 zv = *(const float4*)&zt[grow * 256 + c4];
    ushort4 o; o.x = f2bf(zv.x); o.y = f2bf(zv.y); o.z = f2bf(zv.z); o.w = f2bf(zv.w);
    *(ushort4*)&x[grow * 640 + c4] = o;
    float4 cv = *(const float4*)&cond[grow * 256 + c4];
    ushort4 o2; o2.x = f2bf(cv.x); o2.y = f2bf(cv.y); o2.z = f2bf(cv.z); o2.w = f2bf(cv.w);
    *(ushort4*)&x[grow * 640 + 384 + c4] = o2;
  }

  if (tid < 64) sFreq[tid] = __expf((float)tid * (-9.210340371976184f / 63.0f));
  if (tid < 128) { sB1[tid] = tb1[tid]; sB2[tid] = tb2[tid]; }
  __syncthreads();

  {
    int r = tid >> 2;
    int qd = tid & 3;
    float tv = tin[row0 + r];
    int half = qd >> 1;
    int cbase = (qd & 1) * 32;
    ushort* er = &sE[r * 136 + half * 64 + cbase];
    #pragma unroll
    for (int c = 0; c < 32; ++c) {
      float a = tv * sFreq[cbase + c];
      float v = half ? __cosf(a) : __sinf(a);
      er[c] = f2bf(v);
    }
  }
  __syncthreads();

  const int l = tid & 63;
  const int w = tid >> 6;   // 8 waves: 4(M) x 2(N) grid of 32x64 tiles
  const int wm = w >> 1;
  const int wn = w & 1;
  const int lr = l & 15;
  const int lk = (l >> 4) * 8;
  const int q4 = (l >> 4) * 4;

  f32x4 acc[2][4] = {};
  #pragma unroll
  for (int kk = 0; kk < 4; ++kk) {
    int kb = kk * 32 + lk;
    bf16x8 av[2], bv[4];
    #pragma unroll
    for (int mf = 0; mf < 2; ++mf)
      av[mf] = *(const bf16x8*)&sE[(wm * 32 + mf * 16 + lr) * 136 + kb];
    #pragma unroll
    for (int nf = 0; nf < 4; ++nf)
      bv[nf] = *(const bf16x8*)&tw1t[(size_t)(wn * 64 + nf * 16 + lr) * 128 + kb];
    #pragma unroll
    for (int mf = 0; mf < 2; ++mf)
      #pragma unroll
      for (int nf = 0; nf < 4; ++nf)
        acc[mf][nf] = __builtin_amdgcn_mfma_f32_16x16x32_bf16(av[mf], bv[nf], acc[mf][nf], 0, 0, 0);
  }
  __syncthreads();
  #pragma unroll
  for (int mf = 0; mf < 2; ++mf)
    #pragma unroll
    for (int nf = 0; nf < 4; ++nf) {
      int cc = wn * 64 + nf * 16 + lr;
      #pragma unroll
      for (int rg = 0; rg < 4; ++rg) {
        int rr = wm * 32 + mf * 16 + q4 + rg;
        sE[rr * 136 + cc] = f2bf(silu_f(acc[mf][nf][rg] + sB1[cc]));
      }
    }
  __syncthreads();

  f32x4 acc2[2][4] = {};
  #pragma unroll
  for (int kk = 0; kk < 4; ++kk) {
    int kb = kk * 32 + lk;
    bf16x8 av[2], bv[4];
    #pragma unroll
    for (int mf = 0; mf < 2; ++mf)
      av[mf] = *(const bf16x8*)&sE[(wm * 32 + mf * 16 + lr) * 136 + kb];
    #pragma unroll
    for (int nf = 0; nf < 4; ++nf)
      bv[nf] = *(const bf16x8*)&tw2t[(size_t)(wn * 64 + nf * 16 + lr) * 128 + kb];
    #pragma unroll
    for (int mf = 0; mf < 2; ++mf)
      #pragma unroll
      for (int nf = 0; nf < 4; ++nf)
        acc2[mf][nf] = __builtin_amdgcn_mfma_f32_16x16x32_bf16(av[mf], bv[nf], acc2[mf][nf], 0, 0, 0);
  }
  #pragma unroll
  for (int mf = 0; mf < 2; ++mf)
    #pragma unroll
    for (int nf = 0; nf < 4; ++nf) {
      int cc = wn * 64 + nf * 16 + lr;
      #pragma unroll
      for (int rg = 0; rg < 4; ++rg) {
        int rr = wm * 32 + mf * 16 + q4 + rg;
        x[(size_t)(row0 + rr) * 640 + 256 + cc] = f2bf(acc2[mf][nf][rg] + sB2[cc]);
      }
    }
}

// ---------------- fused router: rh = silu(x@rW1+b1); gate = softmax(rh@rW2+b2) ----------------
__global__ __launch_bounds__(256) void router_kernel(
    const ushort* __restrict__ xb, const ushort* __restrict__ rw1t,
    const float* __restrict__ rb1, const float* __restrict__ rW2,
    const float* __restrict__ rb2, float* __restrict__ gatef,
    float* __restrict__ gateo) {
  __shared__ __align__(16) ushort smA[128 * KSTR];
  __shared__ __align__(16) ushort smB[128 * KSTR];
  __shared__ __align__(16) ushort rhbuf[128 * 136];
  __shared__ float sW2[128 * 8];

  const int tid = threadIdx.x;
  const int row0 = blockIdx.x * 128;
  for (int i = tid; i < 1024; i += 256) sW2[i] = rW2[i];

  const int l = tid & 63;
  const int w = tid >> 6;     // 4 waves: 2x2 of 64x64
  const int wm = w >> 1, wn = w & 1;
  const int lr = l & 15, lk = (l >> 4) * 8, q4 = (l >> 4) * 4;
  const ushort* xrow = xb + (size_t)row0 * 640;

  f32x4 acc[4][4] = {};
  for (int kt = 0; kt < 640; kt += 64) {
    stageA128_256(xrow, 640, kt, smA, tid);
    stageA128_256(rw1t, 640, kt, smB, tid);
    __syncthreads();
    #pragma unroll
    for (int kk = 0; kk < 2; ++kk) {
      int kb = kk * 32 + lk;
      bf16x8 av[4], bv[4];
      #pragma unroll
      for (int mf = 0; mf < 4; ++mf)
        av[mf] = *(const bf16x8*)&smA[(wm * 64 + mf * 16 + lr) * KSTR + kb];
      #pragma unroll
      for (int nf = 0; nf < 4; ++nf)
        bv[nf] = *(const bf16x8*)&smB[(wn * 64 + nf * 16 + lr) * KSTR + kb];
      #pragma unroll
      for (int mf = 0; mf < 4; ++mf)
        #pragma unroll
        for (int nf = 0; nf < 4; ++nf)
          acc[mf][nf] = __builtin_amdgcn_mfma_f32_16x16x32_bf16(av[mf], bv[nf], acc[mf][nf], 0, 0, 0);
    }
    __syncthreads();
  }
  #pragma unroll
  for (int nf = 0; nf < 4; ++nf) {
    int cc = wn * 64 + nf * 16 + lr;
    float b1v = rb1[cc];
    #pragma unroll
    for (int mf = 0; mf < 4; ++mf)
      #pragma unroll
      for (int rg = 0; rg < 4; ++rg) {
        int rr = wm * 64 + mf * 16 + q4 + rg;
        rhbuf[rr * 136 + cc] = f2bf(silu_f(acc[mf][nf][rg] + b1v));
      }
  }
  __syncthreads();

  if (tid < 128) {
    float a[8];
    #pragma unroll
    for (int e = 0; e < 8; ++e) a[e] = rb2[e];
    #pragma unroll
    for (int i8 = 0; i8 < 16; ++i8) {
      bf16x8 hv = *(const bf16x8*)&rhbuf[tid * 136 + i8 * 8];
      #pragma unroll
      for (int j = 0; j < 8; ++j) {
        float h = bf2f((ushort)hv[j]);
        const float* wrow = &sW2[(i8 * 8 + j) * 8];
        #pragma unroll
        for (int e = 0; e < 8; ++e) a[e] += h * wrow[e];
      }
    }
    float mx = a[0];
    #pragma unroll
    for (int e = 1; e < 8; ++e) mx = fmaxf(mx, a[e]);
    float s = 0.f, ex[8];
    #pragma unroll
    for (int e = 0; e < 8; ++e) { ex[e] = __expf(a[e] - mx); s += ex[e]; }
    float inv = 1.f / s;
    size_t b = (size_t)(row0 + tid);
    #pragma unroll
    for (int e = 0; e < 8; ++e) {
      float g = ex[e] * inv;
      gatef[b * 8 + e] = g;
      gateo[b * 8 + e] = g;     // FLOAT32 output
    }
  }
}

// ---- fused MoE, T14 async-stage; __launch_bounds__(512,2) -> 256-VGPR cap, NO spill ----
__global__ __launch_bounds__(512, 2) void moe_fused_kernel(
    const ushort* __restrict__ xb, const ushort* __restrict__ w1t,
    const ushort* __restrict__ w2t, const ushort* __restrict__ w3t,
    const float* __restrict__ eb1, const float* __restrict__ eb2,
    const float* __restrict__ eb3, const float* __restrict__ gatef,
    float* __restrict__ velout) {
  __shared__ __align__(16) ushort smA[128 * KSTR];    // 18 KB: x K-tile
  __shared__ __align__(16) ushort smB[256 * KSTR];    // 36 KB: weight K-tile (N=256)
  __shared__ __align__(16) ushort hbuf[128 * HSTR];   // 66 KB: h tile (padded)
  __shared__ float sGate[128 * 8];
  __shared__ float sEb3[8 * 256];

  const int tid = threadIdx.x;
  const int row0 = blockIdx.x * 128;
  const int l = tid & 63;
  const int w = tid >> 6;     // 8 waves: 2(M) x 4(N), wave tile 64x64
  const int wm = w >> 2;
  const int wn = w & 3;
  const int lr = l & 15;
  const int lk = (l >> 4) * 8;
  const int q4 = (l >> 4) * 4;

  for (int i = tid; i < 1024; i += 512) sGate[i] = gatef[(size_t)row0 * 8 + i];
  for (int i = tid; i < 2048; i += 512) sEb3[i] = eb3[i];

  const ushort* xrow = xb + (size_t)row0 * 640;
  f32x4 vacc[4][4] = {};
  __syncthreads();

  for (int e = 0; e < 8; ++e) {
    const ushort* W1 = w1t + (size_t)e * (256 * 640);
    const ushort* W2 = w2t + (size_t)e * (256 * 256);
    const ushort* W3 = w3t + (size_t)e * (256 * 256);

    // ---- stage 1: h1 = silu(x @ W1 + b1), K=640 ----
    f32x4 acc[4][4] = {};
    {
      uint4 va[2], vb[4];
      loadA128_512(xrow, 640, 0, tid, va);
      loadB256_512(W1, 640, 0, tid, vb);
      writeA128_512(smA, tid, va);
      writeB256_512(smB, tid, vb);
      __syncthreads();
      for (int kt = 0; kt < 640; kt += 64) {
        const bool more = (kt + 64 < 640);
        uint4 na[2], nb[4];
        if (more) {           // issue next-tile loads BEFORE compute: latency hides under MFMA
          loadA128_512(xrow, 640, kt + 64, tid, na);
          loadB256_512(W1, 640, kt + 64, tid, nb);
        }
        #pragma unroll
        for (int kk = 0; kk < 2; ++kk) {
          int kb = kk * 32 + lk;
          bf16x8 av[4], bv[4];
          #pragma unroll
          for (int mf = 0; mf < 4; ++mf)
            av[mf] = *(const bf16x8*)&smA[(wm * 64 + mf * 16 + lr) * KSTR + kb];
          #pragma unroll
          for (int nf = 0; nf < 4; ++nf)
            bv[nf] = *(const bf16x8*)&smB[(wn * 64 + nf * 16 + lr) * KSTR + kb];
          #pragma unroll
          for (int mf = 0; mf < 4; ++mf)
            #pragma unroll
            for (int nf = 0; nf < 4; ++nf)
              acc[mf][nf] = __builtin_amdgcn_mfma_f32_16x16x32_bf16(av[mf], bv[nf], acc[mf][nf], 0, 0, 0);
        }
        __syncthreads();      // all reads of current tile done
        if (more) {
          writeA128_512(smA, tid, na);
          writeB256_512(smB, tid, nb);
        }
        __syncthreads();      // next tile visible
      }
    }
    // epilogue 1 -> hbuf
    #pragma unroll
    for (int nf = 0; nf < 4; ++nf) {
      int cc = wn * 64 + nf * 16 + lr;
      float b1v = eb1[e * 256 + cc];
      #pragma unroll
      for (int mf = 0; mf < 4; ++mf)
        #pragma unroll
        for (int rg = 0; rg < 4; ++rg) {
          int rr = wm * 64 + mf * 16 + q4 + rg;
          hbuf[rr * HSTR + cc] = f2bf(silu_f(acc[mf][nf][rg] + b1v));
        }
    }
    __syncthreads();

    // ---- stage 2: h2g = gate * silu(h1 @ W2 + b2), K=256 ----
    #pragma unroll
    for (int mf = 0; mf < 4; ++mf)
      #pragma unroll
      for (int nf = 0; nf < 4; ++nf)
        acc[mf][nf] = (f32x4){0.f, 0.f, 0.f, 0.f};
    {
      uint4 vb[4];
      loadB256_512(W2, 256, 0, tid, vb);
      writeB256_512(smB, tid, vb);
      __syncthreads();
      for (int kt = 0; kt < 256; kt += 64) {
        const bool more = (kt + 64 < 256);
        uint4 nb[4];
        if (more) loadB256_512(W2, 256, kt + 64, tid, nb);
        #pragma unroll
        for (int kk = 0; kk < 2; ++kk) {
          int kbl = kk * 32 + lk;
          int kbh = kt + kbl;
          bf16x8 av[4], bv[4];
          #pragma unroll
          for (int mf = 0; mf < 4; ++mf)
            av[mf] = *(const bf16x8*)&hbuf[(wm * 64 + mf * 16 + lr) * HSTR + kbh];
          #pragma unroll
          for (int nf = 0; nf < 4; ++nf)
            bv[nf] = *(const bf16x8*)&smB[(wn * 64 + nf * 16 + lr) * KSTR + kbl];
          #pragma unroll
          for (int mf = 0; mf < 4; ++mf)
            #pragma unroll
            for (int nf = 0; nf < 4; ++nf)
              acc[mf][nf] = __builtin_amdgcn_mfma_f32_16x16x32_bf16(av[mf], bv[nf], acc[mf][nf], 0, 0, 0);
        }
        __syncthreads();
        if (more) writeB256_512(smB, tid, nb);
        __syncthreads();
      }
    }
    // epilogue 2 -> hbuf (gate folded in; all reads drained by last barrier)
    #pragma unroll
    for (int nf = 0; nf < 4; ++nf) {
      int cc = wn * 64 + nf * 16 + lr;
      float b2v = eb2[e * 256 + cc];
      #pragma unroll
      for (int mf = 0; mf < 4; ++mf)
        #pragma unroll
        for (int rg = 0; rg < 4; ++rg) {
          int rr = wm * 64 + mf * 16 + q4 + rg;
          float gv = sGate[rr * 8 + e];
          hbuf[rr * HSTR + cc] = f2bf(silu_f(acc[mf][nf][rg] + b2v) * gv);
        }
    }
    __syncthreads();

    // ---- stage 3: vacc += h2g @ W3, K=256 ----
    {
      uint4 vb[4];
      loadB256_512(W3, 256, 0, tid, vb);
      writeB256_512(smB, tid, vb);
      __syncthreads();
      for (int kt = 0; kt < 256; kt += 64) {
        const bool more = (kt + 64 < 256);
        uint4 nb[4];
        if (more) loadB256_512(W3, 256, kt + 64, tid, nb);
        #pragma unroll
        for (int kk = 0; kk < 2; ++kk) {
          int kbl = kk * 32 + lk;
          int kbh = kt + kbl;
          bf16x8 av[4], bv[4];
          #pragma unroll
          for (int mf = 0; mf < 4; ++mf)
            av[mf] = *(const bf16x8*)&hbuf[(wm * 64 + mf * 16 + lr) * HSTR + kbh];
          #pragma unroll
          for (int nf = 0; nf < 4; ++nf)
            bv[nf] = *(const bf16x8*)&smB[(wn * 64 + nf * 16 + lr) * KSTR + kbl];
          #pragma unroll
          for (int mf = 0; mf < 4; ++mf)
            #pragma unroll
            for (int nf = 0; nf < 4; ++nf)
              vacc[mf][nf] = __builtin_amdgcn_mfma_f32_16x16x32_bf16(av[mf], bv[nf], vacc[mf][nf], 0, 0, 0);
        }
        __syncthreads();
        if (more) writeB256_512(smB, tid, nb);
        __syncthreads();
      }
    }
  }

  // final epilogue: velocity = vacc + sum_e gate_e * eb3_e  (FLOAT32 out)
  #pragma unroll
  for (int mf = 0; mf < 4; ++mf)
    #pragma unroll
    for (int rg = 0; rg < 4; ++rg) {
      int rr = wm * 64 + mf * 16 + q4 + rg;
      const float* gp = &sGate[rr * 8];
      #pragma unroll
      for (int nf = 0; nf < 4; ++nf) {
        int cc = wn * 64 + nf * 16 + lr;
        float bsum = 0.f;
        #pragma unroll
        for (int ee = 0; ee < 8; ++ee) bsum += gp[ee] * sEb3[ee * 256 + cc];
        velout[(size_t)(row0 + rr) * D_EMBED + cc] = vacc[mf][nf][rg] + bsum;
      }
    }
}

extern "C" void kernel_launch(void* const* d_in, const int* in_sizes, int n_in,
                              void* d_out, int out_size, void* d_ws, size_t ws_size,
                              hipStream_t stream) {
  const float* zt   = (const float*)d_in[0];
  const float* tin  = (const float*)d_in[1];
  const float* cond = (const float*)d_in[2];
  const float* tW1  = (const float*)d_in[3];
  const float* tb1  = (const float*)d_in[4];
  const float* tW2  = (const float*)d_in[5];
  const float* tb2  = (const float*)d_in[6];
  const float* eW1  = (const float*)d_in[7];
  const float* eb1  = (const float*)d_in[8];
  const float* eW2  = (const float*)d_in[9];
  const float* eb2  = (const float*)d_in[10];
  const float* eW3  = (const float*)d_in[11];
  const float* eb3  = (const float*)d_in[12];
  const float* rW1  = (const float*)d_in[13];
  const float* rb1  = (const float*)d_in[14];
  const float* rW2  = (const float*)d_in[15];
  const float* rb2  = (const float*)d_in[16];

  char* wp = (char*)d_ws;
  ushort* xb    = (ushort*)wp; wp += (size_t)NB_ROWS * D_IN * 2;        // 80 MiB
  float*  gatef = (float*)wp;  wp += (size_t)NB_ROWS * 8 * 4;           // 2 MiB
  ushort* w1t   = (ushort*)wp; wp += (size_t)N_EXP * D_HID * D_IN * 2;
  ushort* w2t   = (ushort*)wp; wp += (size_t)N_EXP * D_HID * D_HID * 2;
  ushort* w3t   = (ushort*)wp; wp += (size_t)N_EXP * D_HID * D_EMBED * 2;
  ushort* rw1t  = (ushort*)wp; wp += (size_t)D_RHID * D_IN * 2;
  ushort* tw1t  = (ushort*)wp; wp += (size_t)128 * 128 * 2;
  ushort* tw2t  = (ushort*)wp; wp += (size_t)128 * 128 * 2;
  // total ~87 MiB (proven safe)

  // FLOAT32 outputs (reference returns jnp.float32)
  float* velout  = (float*)d_out;
  float* gateout = velout + (size_t)NB_ROWS * D_EMBED;

  // weight prep
  {
    int tot;
    tot = 128 * 128;
    prep_transpose<<<(tot + 255) / 256, 256, 0, stream>>>(tW1, tw1t, 128, 128, tot);
    prep_transpose<<<(tot + 255) / 256, 256, 0, stream>>>(tW2, tw2t, 128, 128, tot);
    tot = D_IN * D_RHID;
    prep_transpose<<<(tot + 255) / 256, 256, 0, stream>>>(rW1, rw1t, D_IN, D_RHID, tot);
    tot = N_EXP * D_IN * D_HID;
    prep_transpose<<<(tot + 255) / 256, 256, 0, stream>>>(eW1, w1t, D_IN, D_HID, tot);
    tot = N_EXP * D_HID * D_HID;
    prep_transpose<<<(tot + 255) / 256, 256, 0, stream>>>(eW2, w2t, D_HID, D_HID, tot);
    tot = N_EXP * D_HID * D_EMBED;
    prep_transpose<<<(tot + 255) / 256, 256, 0, stream>>>(eW3, w3t, D_HID, D_EMBED, tot);
  }

  time_x_kernel<<<512, 512, 0, stream>>>(zt, tin, cond, tw1t, tw2t, tb1, tb2, xb);
  router_kernel<<<512, 256, 0, stream>>>(xb, rw1t, rb1, rW2, rb2, gatef, gateout);
  moe_fused_kernel<<<512, 512, 0, stream>>>(xb, w1t, w2t, w3t, eb1, eb2, eb3, gatef, velout);
}

// Round 12
// 1006.981 us; speedup vs baseline: 1.0922x; 1.0242x over previous
//
#include <hip/hip_runtime.h>

typedef __attribute__((ext_vector_type(8))) short bf16x8;
typedef __attribute__((ext_vector_type(4))) float f32x4;

#define NB_ROWS 65536
#define D_EMBED 256
#define D_HID   256
#define N_EXP   8
#define D_RHID  128
#define D_IN    640

#define KSTR 72   // router K-tile stride (padded family, unchanged)

static __device__ __forceinline__ ushort f2bf(float f) {
  union { float f; unsigned u; } v; v.f = f;
  unsigned r = v.u + 0x7fffu + ((v.u >> 16) & 1u);
  return (ushort)(r >> 16);
}
static __device__ __forceinline__ float bf2f(ushort h) {
  union { unsigned u; float f; } v; v.u = ((unsigned)h) << 16;
  return v.f;
}
static __device__ __forceinline__ float silu_f(float x) {
  return x / (1.0f + __expf(-x));
}

// XOR swizzles (write AND read sides both swizzled — reg-staged LDS only).
// K-tile [rows][64]: 8x 16B slots/row, slot ^= row&7 -> 16-lane column reads = 2-way (free)
static __device__ __forceinline__ int kswz(int r, int c) {
  return r * 64 + ((((c) >> 3) ^ (r & 7)) << 3) + ((c) & 7);
}
// h-tile [rows][256]: 32x 16B slots/row, slot ^= row&7
static __device__ __forceinline__ int hswz(int r, int c) {
  return r * 256 + ((((c) >> 3) ^ (r & 7)) << 3) + ((c) & 7);
}

// ---------------- weight prep: [nm][R][C] f32 -> [nm][C][R] bf16 ----------------
__global__ void prep_transpose(const float* __restrict__ src, ushort* __restrict__ dst,
                               int R, int C, int total) {
  int idx = blockIdx.x * 256 + threadIdx.x;
  if (idx >= total) return;
  int rc = R * C;
  int m = idx / rc;
  int rem = idx - m * rc;
  int r = rem / C;
  int c = rem - r * C;
  dst[m * rc + c * R + r] = f2bf(src[idx]);
}

// ---- moe staging (NT=256, swizzled) ----
// [64 rows][64 cols] bf16 K-tile: 2 x 16B per thread
static __device__ __forceinline__ void stageA64s(const ushort* __restrict__ src, int ld,
                                                 int kt, ushort* dst, int tid) {
  uint4 v[2];
  #pragma unroll
  for (int c = 0; c < 2; ++c) {
    int f = c * 4096 + tid * 16;
    int r = f >> 7, ce = (f & 127) >> 1;
    v[c] = *(const uint4*)&src[(size_t)r * ld + kt + ce];
  }
  #pragma unroll
  for (int c = 0; c < 2; ++c) {
    int f = c * 4096 + tid * 16;
    int r = f >> 7, ce = (f & 127) >> 1;
    *(uint4*)&dst[kswz(r, ce)] = v[c];
  }
}
// [256 rows][64 cols] bf16 K-tile: 8 x 16B per thread
static __device__ __forceinline__ void stageB256s(const ushort* __restrict__ src, int ld,
                                                  int kt, ushort* dst, int tid) {
  uint4 v[8];
  #pragma unroll
  for (int c = 0; c < 8; ++c) {
    int f = c * 4096 + tid * 16;
    int r = f >> 7, ce = (f & 127) >> 1;
    v[c] = *(const uint4*)&src[(size_t)r * ld + kt + ce];
  }
  #pragma unroll
  for (int c = 0; c < 8; ++c) {
    int f = c * 4096 + tid * 16;
    int r = f >> 7, ce = (f & 127) >> 1;
    *(uint4*)&dst[kswz(r, ce)] = v[c];
  }
}
// [128 rows][64 cols] bf16 K-tile, NT=256 (router, padded KSTR family)
static __device__ __forceinline__ void stageA128_256(const ushort* __restrict__ src, int ld,
                                                     int kt, ushort* dst, int tid) {
  uint4 v[4];
  #pragma unroll
  for (int c = 0; c < 4; ++c) {
    int f = c * 4096 + tid * 16;
    int r = f >> 7, ce = (f & 127) >> 1;
    v[c] = *(const uint4*)&src[(size_t)r * ld + kt + ce];
  }
  #pragma unroll
  for (int c = 0; c < 4; ++c) {
    int f = c * 4096 + tid * 16;
    int r = f >> 7, ce = (f & 127) >> 1;
    *(uint4*)&dst[r * KSTR + ce] = v[c];
  }
}

// ---------------- time embedding MLP + build x = [z | te | cond] (bf16) ----------------
__global__ __launch_bounds__(512) void time_x_kernel(
    const float* __restrict__ zt, const float* __restrict__ tin,
    const float* __restrict__ cond,
    const ushort* __restrict__ tw1t, const ushort* __restrict__ tw2t,
    const float* __restrict__ tb1, const float* __restrict__ tb2,
    ushort* __restrict__ x) {
  __shared__ __align__(16) ushort sE[128 * 136];
  __shared__ float sFreq[64];
  __shared__ float sB1[128];
  __shared__ float sB2[128];

  const int tid = threadIdx.x;
  const int row0 = blockIdx.x * 128;

  for (int ch = tid; ch < 128 * 64; ch += 512) {
    int r = ch >> 6;
    int c4 = (ch & 63) << 2;
    size_t grow = (size_t)(row0 + r);
    float4 zv = *(const float4*)&zt[grow * 256 + c4];
    ushort4 o; o.x = f2bf(zv.x); o.y = f2bf(zv.y); o.z = f2bf(zv.z); o.w = f2bf(zv.w);
    *(ushort4*)&x[grow * 640 + c4] = o;
    float4 cv = *(const float4*)&cond[grow * 256 + c4];
    ushort4 o2; o2.x = f2bf(cv.x); o2.y = f2bf(cv.y); o2.z = f2bf(cv.z); o2.w = f2bf(cv.w);
    *(ushort4*)&x[grow * 640 + 384 + c4] = o2;
  }

  if (tid < 64) sFreq[tid] = __expf((float)tid * (-9.210340371976184f / 63.0f));
  if (tid < 128) { sB1[tid] = tb1[tid]; sB2[tid] = tb2[tid]; }
  __syncthreads();

  {
    int r = tid >> 2;
    int qd = tid & 3;
    float tv = tin[row0 + r];
    int half = qd >> 1;
    int cbase = (qd & 1) * 32;
    ushort* er = &sE[r * 136 + half * 64 + cbase];
    #pragma unroll
    for (int c = 0; c < 32; ++c) {
      float a = tv * sFreq[cbase + c];
      float v = half ? __cosf(a) : __sinf(a);
      er[c] = f2bf(v);
    }
  }
  __syncthreads();

  const int l = tid & 63;
  const int w = tid >> 6;   // 8 waves: 4(M) x 2(N) of 32x64
  const int wm = w >> 1;
  const int wn = w & 1;
  const int lr = l & 15;
  const int lk = (l >> 4) * 8;
  const int q4 = (l >> 4) * 4;

  f32x4 acc[2][4] = {};
  #pragma unroll
  for (int kk = 0; kk < 4; ++kk) {
    int kb = kk * 32 + lk;
    bf16x8 av[2], bv[4];
    #pragma unroll
    for (int mf = 0; mf < 2; ++mf)
      av[mf] = *(const bf16x8*)&sE[(wm * 32 + mf * 16 + lr) * 136 + kb];
    #pragma unroll
    for (int nf = 0; nf < 4; ++nf)
      bv[nf] = *(const bf16x8*)&tw1t[(size_t)(wn * 64 + nf * 16 + lr) * 128 + kb];
    #pragma unroll
    for (int mf = 0; mf < 2; ++mf)
      #pragma unroll
      for (int nf = 0; nf < 4; ++nf)
        acc[mf][nf] = __builtin_amdgcn_mfma_f32_16x16x32_bf16(av[mf], bv[nf], acc[mf][nf], 0, 0, 0);
  }
  __syncthreads();
  #pragma unroll
  for (int mf = 0; mf < 2; ++mf)
    #pragma unroll
    for (int nf = 0; nf < 4; ++nf) {
      int cc = wn * 64 + nf * 16 + lr;
      #pragma unroll
      for (int rg = 0; rg < 4; ++rg) {
        int rr = wm * 32 + mf * 16 + q4 + rg;
        sE[rr * 136 + cc] = f2bf(silu_f(acc[mf][nf][rg] + sB1[cc]));
      }
    }
  __syncthreads();

  f32x4 acc2[2][4] = {};
  #pragma unroll
  for (int kk = 0; kk < 4; ++kk) {
    int kb = kk * 32 + lk;
    bf16x8 av[2], bv[4];
    #pragma unroll
    for (int mf = 0; mf < 2; ++mf)
      av[mf] = *(const bf16x8*)&sE[(wm * 32 + mf * 16 + lr) * 136 + kb];
    #pragma unroll
    for (int nf = 0; nf < 4; ++nf)
      bv[nf] = *(const bf16x8*)&tw2t[(size_t)(wn * 64 + nf * 16 + lr) * 128 + kb];
    #pragma unroll
    for (int mf = 0; mf < 2; ++mf)
      #pragma unroll
      for (int nf = 0; nf < 4; ++nf)
        acc2[mf][nf] = __builtin_amdgcn_mfma_f32_16x16x32_bf16(av[mf], bv[nf], acc2[mf][nf], 0, 0, 0);
  }
  #pragma unroll
  for (int mf = 0; mf < 2; ++mf)
    #pragma unroll
    for (int nf = 0; nf < 4; ++nf) {
      int cc = wn * 64 + nf * 16 + lr;
      #pragma unroll
      for (int rg = 0; rg < 4; ++rg) {
        int rr = wm * 32 + mf * 16 + q4 + rg;
        x[(size_t)(row0 + rr) * 640 + 256 + cc] = f2bf(acc2[mf][nf][rg] + sB2[cc]);
      }
    }
}

// ---------------- fused router (unchanged from round 8) ----------------
__global__ __launch_bounds__(256) void router_kernel(
    const ushort* __restrict__ xb, const ushort* __restrict__ rw1t,
    const float* __restrict__ rb1, const float* __restrict__ rW2,
    const float* __restrict__ rb2, float* __restrict__ gatef,
    float* __restrict__ gateo) {
  __shared__ __align__(16) ushort smA[128 * KSTR];
  __shared__ __align__(16) ushort smB[128 * KSTR];
  __shared__ __align__(16) ushort rhbuf[128 * 136];
  __shared__ float sW2[128 * 8];

  const int tid = threadIdx.x;
  const int row0 = blockIdx.x * 128;
  for (int i = tid; i < 1024; i += 256) sW2[i] = rW2[i];

  const int l = tid & 63;
  const int w = tid >> 6;     // 4 waves: 2x2 of 64x64
  const int wm = w >> 1, wn = w & 1;
  const int lr = l & 15, lk = (l >> 4) * 8, q4 = (l >> 4) * 4;
  const ushort* xrow = xb + (size_t)row0 * 640;

  f32x4 acc[4][4] = {};
  for (int kt = 0; kt < 640; kt += 64) {
    stageA128_256(xrow, 640, kt, smA, tid);
    stageA128_256(rw1t, 640, kt, smB, tid);
    __syncthreads();
    #pragma unroll
    for (int kk = 0; kk < 2; ++kk) {
      int kb = kk * 32 + lk;
      bf16x8 av[4], bv[4];
      #pragma unroll
      for (int mf = 0; mf < 4; ++mf)
        av[mf] = *(const bf16x8*)&smA[(wm * 64 + mf * 16 + lr) * KSTR + kb];
      #pragma unroll
      for (int nf = 0; nf < 4; ++nf)
        bv[nf] = *(const bf16x8*)&smB[(wn * 64 + nf * 16 + lr) * KSTR + kb];
      #pragma unroll
      for (int mf = 0; mf < 4; ++mf)
        #pragma unroll
        for (int nf = 0; nf < 4; ++nf)
          acc[mf][nf] = __builtin_amdgcn_mfma_f32_16x16x32_bf16(av[mf], bv[nf], acc[mf][nf], 0, 0, 0);
    }
    __syncthreads();
  }
  #pragma unroll
  for (int nf = 0; nf < 4; ++nf) {
    int cc = wn * 64 + nf * 16 + lr;
    float b1v = rb1[cc];
    #pragma unroll
    for (int mf = 0; mf < 4; ++mf)
      #pragma unroll
      for (int rg = 0; rg < 4; ++rg) {
        int rr = wm * 64 + mf * 16 + q4 + rg;
        rhbuf[rr * 136 + cc] = f2bf(silu_f(acc[mf][nf][rg] + b1v));
      }
  }
  __syncthreads();

  if (tid < 128) {
    float a[8];
    #pragma unroll
    for (int e = 0; e < 8; ++e) a[e] = rb2[e];
    #pragma unroll
    for (int i8 = 0; i8 < 16; ++i8) {
      bf16x8 hv = *(const bf16x8*)&rhbuf[tid * 136 + i8 * 8];
      #pragma unroll
      for (int j = 0; j < 8; ++j) {
        float h = bf2f((ushort)hv[j]);
        const float* wrow = &sW2[(i8 * 8 + j) * 8];
        #pragma unroll
        for (int e = 0; e < 8; ++e) a[e] += h * wrow[e];
      }
    }
    float mx = a[0];
    #pragma unroll
    for (int e = 1; e < 8; ++e) mx = fmaxf(mx, a[e]);
    float s = 0.f, ex[8];
    #pragma unroll
    for (int e = 0; e < 8; ++e) { ex[e] = __expf(a[e] - mx); s += ex[e]; }
    float inv = 1.f / s;
    size_t b = (size_t)(row0 + tid);
    #pragma unroll
    for (int e = 0; e < 8; ++e) {
      float g = ex[e] * inv;
      gatef[b * 8 + e] = g;
      gateo[b * 8 + e] = g;     // FLOAT32 output
    }
  }
}

// ---- fused MoE: BM=64, 256 threads, 74KB LDS, swizzled -> 2 blocks/CU, no spill ----
__global__ __launch_bounds__(256, 2) void moe_fused_kernel(
    const ushort* __restrict__ xb, const ushort* __restrict__ w1t,
    const ushort* __restrict__ w2t, const ushort* __restrict__ w3t,
    const float* __restrict__ eb1, const float* __restrict__ eb2,
    const float* __restrict__ eb3, const float* __restrict__ gatef,
    float* __restrict__ velout) {
  __shared__ __align__(16) ushort smA[64 * 64];     //  8 KB: x K-tile (swizzled)
  __shared__ __align__(16) ushort smB[256 * 64];    // 32 KB: weight K-tile (swizzled)
  __shared__ __align__(16) ushort hbuf[64 * 256];   // 32 KB: h tile (swizzled)
  __shared__ float sGate[64 * 8];                   //  2 KB
  // total 74 KB -> 2 blocks/CU; regs: acc+vacc=128 + ~100 arch <= 256/wave at 2 waves/SIMD

  const int tid = threadIdx.x;
  const int row0 = blockIdx.x * 64;
  const int l = tid & 63;
  const int w = tid >> 6;     // 4 waves: 2(M) x 2(N), wave tile 32 rows x 128 cols
  const int wm = w >> 1;
  const int wn = w & 1;
  const int lr = l & 15;
  const int lk = (l >> 4) * 8;
  const int q4 = (l >> 4) * 4;

  for (int i = tid; i < 512; i += 256) sGate[i] = gatef[(size_t)row0 * 8 + i];

  const ushort* xrow = xb + (size_t)row0 * 640;
  f32x4 vacc[2][8] = {};
  __syncthreads();

  for (int e = 0; e < 8; ++e) {
    const ushort* W1 = w1t + (size_t)e * (256 * 640);
    const ushort* W2 = w2t + (size_t)e * (256 * 256);
    const ushort* W3 = w3t + (size_t)e * (256 * 256);

    // ---- stage 1: h1 = silu(x @ W1 + b1), K=640 ----
    f32x4 acc[2][8] = {};
    for (int kt = 0; kt < 640; kt += 64) {
      stageA64s(xrow, 640, kt, smA, tid);
      stageB256s(W1, 640, kt, smB, tid);
      __syncthreads();
      #pragma unroll
      for (int kk = 0; kk < 2; ++kk) {
        int kb = kk * 32 + lk;
        bf16x8 av[2], bv[8];
        #pragma unroll
        for (int mf = 0; mf < 2; ++mf)
          av[mf] = *(const bf16x8*)&smA[kswz(wm * 32 + mf * 16 + lr, kb)];
        #pragma unroll
        for (int nf = 0; nf < 8; ++nf)
          bv[nf] = *(const bf16x8*)&smB[kswz(wn * 128 + nf * 16 + lr, kb)];
        #pragma unroll
        for (int mf = 0; mf < 2; ++mf)
          #pragma unroll
          for (int nf = 0; nf < 8; ++nf)
            acc[mf][nf] = __builtin_amdgcn_mfma_f32_16x16x32_bf16(av[mf], bv[nf], acc[mf][nf], 0, 0, 0);
      }
      __syncthreads();
    }
    // epilogue 1 -> hbuf (swizzled)
    #pragma unroll
    for (int nf = 0; nf < 8; ++nf) {
      int cc = wn * 128 + nf * 16 + lr;
      float b1v = eb1[e * 256 + cc];
      #pragma unroll
      for (int mf = 0; mf < 2; ++mf)
        #pragma unroll
        for (int rg = 0; rg < 4; ++rg) {
          int rr = wm * 32 + mf * 16 + q4 + rg;
          hbuf[hswz(rr, cc)] = f2bf(silu_f(acc[mf][nf][rg] + b1v));
        }
    }
    __syncthreads();

    // ---- stage 2: h2g = gate * silu(h1 @ W2 + b2), K=256 ----
    #pragma unroll
    for (int mf = 0; mf < 2; ++mf)
      #pragma unroll
      for (int nf = 0; nf < 8; ++nf)
        acc[mf][nf] = (f32x4){0.f, 0.f, 0.f, 0.f};
    for (int kt = 0; kt < 256; kt += 64) {
      stageB256s(W2, 256, kt, smB, tid);
      __syncthreads();
      #pragma unroll
      for (int kk = 0; kk < 2; ++kk) {
        int kbl = kk * 32 + lk;
        int kbh = kt + kbl;
        bf16x8 av[2], bv[8];
        #pragma unroll
        for (int mf = 0; mf < 2; ++mf)
          av[mf] = *(const bf16x8*)&hbuf[hswz(wm * 32 + mf * 16 + lr, kbh)];
        #pragma unroll
        for (int nf = 0; nf < 8; ++nf)
          bv[nf] = *(const bf16x8*)&smB[kswz(wn * 128 + nf * 16 + lr, kbl)];
        #pragma unroll
        for (int mf = 0; mf < 2; ++mf)
          #pragma unroll
          for (int nf = 0; nf < 8; ++nf)
            acc[mf][nf] = __builtin_amdgcn_mfma_f32_16x16x32_bf16(av[mf], bv[nf], acc[mf][nf], 0, 0, 0);
      }
      __syncthreads();
    }
    // epilogue 2 -> hbuf (gate folded in; reads drained by trailing barrier)
    #pragma unroll
    for (int nf = 0; nf < 8; ++nf) {
      int cc = wn * 128 + nf * 16 + lr;
      float b2v = eb2[e * 256 + cc];
      #pragma unroll
      for (int mf = 0; mf < 2; ++mf)
        #pragma unroll
        for (int rg = 0; rg < 4; ++rg) {
          int rr = wm * 32 + mf * 16 + q4 + rg;
          float gv = sGate[rr * 8 + e];
          hbuf[hswz(rr, cc)] = f2bf(silu_f(acc[mf][nf][rg] + b2v) * gv);
        }
    }
    __syncthreads();

    // ---- stage 3: vacc += h2g @ W3, K=256 ----
    for (int kt = 0; kt < 256; kt += 64) {
      stageB256s(W3, 256, kt, smB, tid);
      __syncthreads();
      #pragma unroll
      for (int kk = 0; kk < 2; ++kk) {
        int kbl = kk * 32 + lk;
        int kbh = kt + kbl;
        bf16x8 av[2], bv[8];
        #pragma unroll
        for (int mf = 0; mf < 2; ++mf)
          av[mf] = *(const bf16x8*)&hbuf[hswz(wm * 32 + mf * 16 + lr, kbh)];
        #pragma unroll
        for (int nf = 0; nf < 8; ++nf)
          bv[nf] = *(const bf16x8*)&smB[kswz(wn * 128 + nf * 16 + lr, kbl)];
        #pragma unroll
        for (int mf = 0; mf < 2; ++mf)
          #pragma unroll
          for (int nf = 0; nf < 8; ++nf)
            vacc[mf][nf] = __builtin_amdgcn_mfma_f32_16x16x32_bf16(av[mf], bv[nf], vacc[mf][nf], 0, 0, 0);
      }
      __syncthreads();
    }
  }

  // stage eb3 into smA's space (free now; trailing barrier above drained K-loop)
  float* eL = (float*)smA;   // 2048 f32 = 8 KB = smA exactly
  for (int i = tid; i < 2048; i += 256) eL[i] = eb3[i];
  __syncthreads();
  #pragma unroll
  for (int mf = 0; mf < 2; ++mf)
    #pragma unroll
    for (int rg = 0; rg < 4; ++rg) {
      int rr = wm * 32 + mf * 16 + q4 + rg;
      const float* gp = &sGate[rr * 8];
      #pragma unroll
      for (int nf = 0; nf < 8; ++nf) {
        int cc = wn * 128 + nf * 16 + lr;
        float bsum = 0.f;
        #pragma unroll
        for (int ee = 0; ee < 8; ++ee) bsum += gp[ee] * eL[ee * 256 + cc];
        velout[(size_t)(row0 + rr) * D_EMBED + cc] = vacc[mf][nf][rg] + bsum;
      }
    }
}

extern "C" void kernel_launch(void* const* d_in, const int* in_sizes, int n_in,
                              void* d_out, int out_size, void* d_ws, size_t ws_size,
                              hipStream_t stream) {
  const float* zt   = (const float*)d_in[0];
  const float* tin  = (const float*)d_in[1];
  const float* cond = (const float*)d_in[2];
  const float* tW1  = (const float*)d_in[3];
  const float* tb1  = (const float*)d_in[4];
  const float* tW2  = (const float*)d_in[5];
  const float* tb2  = (const float*)d_in[6];
  const float* eW1  = (const float*)d_in[7];
  const float* eb1  = (const float*)d_in[8];
  const float* eW2  = (const float*)d_in[9];
  const float* eb2  = (const float*)d_in[10];
  const float* eW3  = (const float*)d_in[11];
  const float* eb3  = (const float*)d_in[12];
  const float* rW1  = (const float*)d_in[13];
  const float* rb1  = (const float*)d_in[14];
  const float* rW2  = (const float*)d_in[15];
  const float* rb2  = (const float*)d_in[16];

  char* wp = (char*)d_ws;
  ushort* xb    = (ushort*)wp; wp += (size_t)NB_ROWS * D_IN * 2;        // 80 MiB
  float*  gatef = (float*)wp;  wp += (size_t)NB_ROWS * 8 * 4;           // 2 MiB
  ushort* w1t   = (ushort*)wp; wp += (size_t)N_EXP * D_HID * D_IN * 2;
  ushort* w2t   = (ushort*)wp; wp += (size_t)N_EXP * D_HID * D_HID * 2;
  ushort* w3t   = (ushort*)wp; wp += (size_t)N_EXP * D_HID * D_EMBED * 2;
  ushort* rw1t  = (ushort*)wp; wp += (size_t)D_RHID * D_IN * 2;
  ushort* tw1t  = (ushort*)wp; wp += (size_t)128 * 128 * 2;
  ushort* tw2t  = (ushort*)wp; wp += (size_t)128 * 128 * 2;
  // total ~87 MiB (proven safe)

  // FLOAT32 outputs (reference returns jnp.float32)
  float* velout  = (float*)d_out;
  float* gateout = velout + (size_t)NB_ROWS * D_EMBED;

  // weight prep
  {
    int tot;
    tot = 128 * 128;
    prep_transpose<<<(tot + 255) / 256, 256, 0, stream>>>(tW1, tw1t, 128, 128, tot);
    prep_transpose<<<(tot + 255) / 256, 256, 0, stream>>>(tW2, tw2t, 128, 128, tot);
    tot = D_IN * D_RHID;
    prep_transpose<<<(tot + 255) / 256, 256, 0, stream>>>(rW1, rw1t, D_IN, D_RHID, tot);
    tot = N_EXP * D_IN * D_HID;
    prep_transpose<<<(tot + 255) / 256, 256, 0, stream>>>(eW1, w1t, D_IN, D_HID, tot);
    tot = N_EXP * D_HID * D_HID;
    prep_transpose<<<(tot + 255) / 256, 256, 0, stream>>>(eW2, w2t, D_HID, D_HID, tot);
    tot = N_EXP * D_HID * D_EMBED;
    prep_transpose<<<(tot + 255) / 256, 256, 0, stream>>>(eW3, w3t, D_HID, D_EMBED, tot);
  }

  time_x_kernel<<<512, 512, 0, stream>>>(zt, tin, cond, tw1t, tw2t, tb1, tb2, xb);
  router_kernel<<<512, 256, 0, stream>>>(xb, rw1t, rb1, rW2, rb2, gatef, gateout);
  moe_fused_kernel<<<1024, 256, 0, stream>>>(xb, w1t, w2t, w3t, eb1, eb2, eb3, gatef, velout);
}

// Round 13
// 837.961 us; speedup vs baseline: 1.3125x; 1.2017x over previous
//
#include <hip/hip_runtime.h>

typedef __attribute__((ext_vector_type(8))) short bf16x8;
typedef __attribute__((ext_vector_type(4))) float f32x4;

#define NB_ROWS 65536
#define D_EMBED 256
#define D_HID   256
#define N_EXP   8
#define D_RHID  128
#define D_IN    640

#define KSTR 72   // router K-tile stride (padded family, unchanged)

static __device__ __forceinline__ ushort f2bf(float f) {
  union { float f; unsigned u; } v; v.f = f;
  unsigned r = v.u + 0x7fffu + ((v.u >> 16) & 1u);
  return (ushort)(r >> 16);
}
static __device__ __forceinline__ float bf2f(ushort h) {
  union { unsigned u; float f; } v; v.u = ((unsigned)h) << 16;
  return v.f;
}
static __device__ __forceinline__ float silu_f(float x) {
  return x / (1.0f + __expf(-x));
}

// XOR swizzles (write AND read sides both swizzled — reg-staged LDS only).
// K-tile [rows][64]: 8x 16B slots/row, slot ^= row&7 -> column reads 2-way (free, m136)
static __device__ __forceinline__ int kswz(int r, int c) {
  return r * 64 + ((((c) >> 3) ^ (r & 7)) << 3) + ((c) & 7);
}
// h-tile [rows][256]: 32x 16B slots/row, slot ^= row&7
static __device__ __forceinline__ int hswz(int r, int c) {
  return r * 256 + ((((c) >> 3) ^ (r & 7)) << 3) + ((c) & 7);
}

// ---------------- weight prep: [nm][R][C] f32 -> [nm][C][R] bf16 ----------------
__global__ void prep_transpose(const float* __restrict__ src, ushort* __restrict__ dst,
                               int R, int C, int total) {
  int idx = blockIdx.x * 256 + threadIdx.x;
  if (idx >= total) return;
  int rc = R * C;
  int m = idx / rc;
  int rem = idx - m * rc;
  int r = rem / C;
  int c = rem - r * C;
  dst[m * rc + c * R + r] = f2bf(src[idx]);
}

// ---- moe staging (NT=512, swizzled; register lifetimes match round 8's no-spill proportions) ----
// [64 rows][64 cols] bf16 K-tile: 1 x 16B per thread
static __device__ __forceinline__ void stageA64_512s(const ushort* __restrict__ src, int ld,
                                                     int kt, ushort* dst, int tid) {
  int f = tid * 16;
  int r = f >> 7, ce = (f & 127) >> 1;
  uint4 v = *(const uint4*)&src[(size_t)r * ld + kt + ce];
  *(uint4*)&dst[kswz(r, ce)] = v;
}
// [256 rows][64 cols] bf16 K-tile: 4 x 16B per thread (v[4] = 16 regs, round-8-proven)
static __device__ __forceinline__ void stageB256_512s(const ushort* __restrict__ src, int ld,
                                                      int kt, ushort* dst, int tid) {
  uint4 v[4];
  #pragma unroll
  for (int c = 0; c < 4; ++c) {
    int f = c * 8192 + tid * 16;
    int r = f >> 7, ce = (f & 127) >> 1;
    v[c] = *(const uint4*)&src[(size_t)r * ld + kt + ce];
  }
  #pragma unroll
  for (int c = 0; c < 4; ++c) {
    int f = c * 8192 + tid * 16;
    int r = f >> 7, ce = (f & 127) >> 1;
    *(uint4*)&dst[kswz(r, ce)] = v[c];
  }
}
// [128 rows][64 cols] bf16 K-tile, NT=256 (router, padded KSTR family)
static __device__ __forceinline__ void stageA128_256(const ushort* __restrict__ src, int ld,
                                                     int kt, ushort* dst, int tid) {
  uint4 v[4];
  #pragma unroll
  for (int c = 0; c < 4; ++c) {
    int f = c * 4096 + tid * 16;
    int r = f >> 7, ce = (f & 127) >> 1;
    v[c] = *(const uint4*)&src[(size_t)r * ld + kt + ce];
  }
  #pragma unroll
  for (int c = 0; c < 4; ++c) {
    int f = c * 4096 + tid * 16;
    int r = f >> 7, ce = (f & 127) >> 1;
    *(uint4*)&dst[r * KSTR + ce] = v[c];
  }
}

// ---------------- time embedding MLP + build x = [z | te | cond] (bf16) ----------------
__global__ __launch_bounds__(512) void time_x_kernel(
    const float* __restrict__ zt, const float* __restrict__ tin,
    const float* __restrict__ cond,
    const ushort* __restrict__ tw1t, const ushort* __restrict__ tw2t,
    const float* __restrict__ tb1, const float* __restrict__ tb2,
    ushort* __restrict__ x) {
  __shared__ __align__(16) ushort sE[128 * 136];
  __shared__ float sFreq[64];
  __shared__ float sB1[128];
  __shared__ float sB2[128];

  const int tid = threadIdx.x;
  const int row0 = blockIdx.x * 128;

  for (int ch = tid; ch < 128 * 64; ch += 512) {
    int r = ch >> 6;
    int c4 = (ch & 63) << 2;
    size_t grow = (size_t)(row0 + r);
    float4 zv = *(const float4*)&zt[grow * 256 + c4];
    ushort4 o; o.x = f2bf(zv.x); o.y = f2bf(zv.y); o.z = f2bf(zv.z); o.w = f2bf(zv.w);
    *(ushort4*)&x[grow * 640 + c4] = o;
    float4 cv = *(const float4*)&cond[grow * 256 + c4];
    ushort4 o2; o2.x = f2bf(cv.x); o2.y = f2bf(cv.y); o2.z = f2bf(cv.z); o2.w = f2bf(cv.w);
    *(ushort4*)&x[grow * 640 + 384 + c4] = o2;
  }

  if (tid < 64) sFreq[tid] = __expf((float)tid * (-9.210340371976184f / 63.0f));
  if (tid < 128) { sB1[tid] = tb1[tid]; sB2[tid] = tb2[tid]; }
  __syncthreads();

  {
    int r = tid >> 2;
    int qd = tid & 3;
    float tv = tin[row0 + r];
    int half = qd >> 1;
    int cbase = (qd & 1) * 32;
    ushort* er = &sE[r * 136 + half * 64 + cbase];
    #pragma unroll
    for (int c = 0; c < 32; ++c) {
      float a = tv * sFreq[cbase + c];
      float v = half ? __cosf(a) : __sinf(a);
      er[c] = f2bf(v);
    }
  }
  __syncthreads();

  const int l = tid & 63;
  const int w = tid >> 6;   // 8 waves: 4(M) x 2(N) of 32x64
  const int wm = w >> 1;
  const int wn = w & 1;
  const int lr = l & 15;
  const int lk = (l >> 4) * 8;
  const int q4 = (l >> 4) * 4;

  f32x4 acc[2][4] = {};
  #pragma unroll
  for (int kk = 0; kk < 4; ++kk) {
    int kb = kk * 32 + lk;
    bf16x8 av[2], bv[4];
    #pragma unroll
    for (int mf = 0; mf < 2; ++mf)
      av[mf] = *(const bf16x8*)&sE[(wm * 32 + mf * 16 + lr) * 136 + kb];
    #pragma unroll
    for (int nf = 0; nf < 4; ++nf)
      bv[nf] = *(const bf16x8*)&tw1t[(size_t)(wn * 64 + nf * 16 + lr) * 128 + kb];
    #pragma unroll
    for (int mf = 0; mf < 2; ++mf)
      #pragma unroll
      for (int nf = 0; nf < 4; ++nf)
        acc[mf][nf] = __builtin_amdgcn_mfma_f32_16x16x32_bf16(av[mf], bv[nf], acc[mf][nf], 0, 0, 0);
  }
  __syncthreads();
  #pragma unroll
  for (int mf = 0; mf < 2; ++mf)
    #pragma unroll
    for (int nf = 0; nf < 4; ++nf) {
      int cc = wn * 64 + nf * 16 + lr;
      #pragma unroll
      for (int rg = 0; rg < 4; ++rg) {
        int rr = wm * 32 + mf * 16 + q4 + rg;
        sE[rr * 136 + cc] = f2bf(silu_f(acc[mf][nf][rg] + sB1[cc]));
      }
    }
  __syncthreads();

  f32x4 acc2[2][4] = {};
  #pragma unroll
  for (int kk = 0; kk < 4; ++kk) {
    int kb = kk * 32 + lk;
    bf16x8 av[2], bv[4];
    #pragma unroll
    for (int mf = 0; mf < 2; ++mf)
      av[mf] = *(const bf16x8*)&sE[(wm * 32 + mf * 16 + lr) * 136 + kb];
    #pragma unroll
    for (int nf = 0; nf < 4; ++nf)
      bv[nf] = *(const bf16x8*)&tw2t[(size_t)(wn * 64 + nf * 16 + lr) * 128 + kb];
    #pragma unroll
    for (int mf = 0; mf < 2; ++mf)
      #pragma unroll
      for (int nf = 0; nf < 4; ++nf)
        acc2[mf][nf] = __builtin_amdgcn_mfma_f32_16x16x32_bf16(av[mf], bv[nf], acc2[mf][nf], 0, 0, 0);
  }
  #pragma unroll
  for (int mf = 0; mf < 2; ++mf)
    #pragma unroll
    for (int nf = 0; nf < 4; ++nf) {
      int cc = wn * 64 + nf * 16 + lr;
      #pragma unroll
      for (int rg = 0; rg < 4; ++rg) {
        int rr = wm * 32 + mf * 16 + q4 + rg;
        x[(size_t)(row0 + rr) * 640 + 256 + cc] = f2bf(acc2[mf][nf][rg] + sB2[cc]);
      }
    }
}

// ---------------- fused router (unchanged, proven) ----------------
__global__ __launch_bounds__(256) void router_kernel(
    const ushort* __restrict__ xb, const ushort* __restrict__ rw1t,
    const float* __restrict__ rb1, const float* __restrict__ rW2,
    const float* __restrict__ rb2, float* __restrict__ gatef,
    float* __restrict__ gateo) {
  __shared__ __align__(16) ushort smA[128 * KSTR];
  __shared__ __align__(16) ushort smB[128 * KSTR];
  __shared__ __align__(16) ushort rhbuf[128 * 136];
  __shared__ float sW2[128 * 8];

  const int tid = threadIdx.x;
  const int row0 = blockIdx.x * 128;
  for (int i = tid; i < 1024; i += 256) sW2[i] = rW2[i];

  const int l = tid & 63;
  const int w = tid >> 6;     // 4 waves: 2x2 of 64x64
  const int wm = w >> 1, wn = w & 1;
  const int lr = l & 15, lk = (l >> 4) * 8, q4 = (l >> 4) * 4;
  const ushort* xrow = xb + (size_t)row0 * 640;

  f32x4 acc[4][4] = {};
  for (int kt = 0; kt < 640; kt += 64) {
    stageA128_256(xrow, 640, kt, smA, tid);
    stageA128_256(rw1t, 640, kt, smB, tid);
    __syncthreads();
    #pragma unroll
    for (int kk = 0; kk < 2; ++kk) {
      int kb = kk * 32 + lk;
      bf16x8 av[4], bv[4];
      #pragma unroll
      for (int mf = 0; mf < 4; ++mf)
        av[mf] = *(const bf16x8*)&smA[(wm * 64 + mf * 16 + lr) * KSTR + kb];
      #pragma unroll
      for (int nf = 0; nf < 4; ++nf)
        bv[nf] = *(const bf16x8*)&smB[(wn * 64 + nf * 16 + lr) * KSTR + kb];
      #pragma unroll
      for (int mf = 0; mf < 4; ++mf)
        #pragma unroll
        for (int nf = 0; nf < 4; ++nf)
          acc[mf][nf] = __builtin_amdgcn_mfma_f32_16x16x32_bf16(av[mf], bv[nf], acc[mf][nf], 0, 0, 0);
    }
    __syncthreads();
  }
  #pragma unroll
  for (int nf = 0; nf < 4; ++nf) {
    int cc = wn * 64 + nf * 16 + lr;
    float b1v = rb1[cc];
    #pragma unroll
    for (int mf = 0; mf < 4; ++mf)
      #pragma unroll
      for (int rg = 0; rg < 4; ++rg) {
        int rr = wm * 64 + mf * 16 + q4 + rg;
        rhbuf[rr * 136 + cc] = f2bf(silu_f(acc[mf][nf][rg] + b1v));
      }
  }
  __syncthreads();

  if (tid < 128) {
    float a[8];
    #pragma unroll
    for (int e = 0; e < 8; ++e) a[e] = rb2[e];
    #pragma unroll
    for (int i8 = 0; i8 < 16; ++i8) {
      bf16x8 hv = *(const bf16x8*)&rhbuf[tid * 136 + i8 * 8];
      #pragma unroll
      for (int j = 0; j < 8; ++j) {
        float h = bf2f((ushort)hv[j]);
        const float* wrow = &sW2[(i8 * 8 + j) * 8];
        #pragma unroll
        for (int e = 0; e < 8; ++e) a[e] += h * wrow[e];
      }
    }
    float mx = a[0];
    #pragma unroll
    for (int e = 1; e < 8; ++e) mx = fmaxf(mx, a[e]);
    float s = 0.f, ex[8];
    #pragma unroll
    for (int e = 0; e < 8; ++e) { ex[e] = __expf(a[e] - mx); s += ex[e]; }
    float inv = 1.f / s;
    size_t b = (size_t)(row0 + tid);
    #pragma unroll
    for (int e = 0; e < 8; ++e) {
      float g = ex[e] * inv;
      gatef[b * 8 + e] = g;
      gateo[b * 8 + e] = g;     // FLOAT32 output
    }
  }
}

// ---- fused MoE: BM=64 x NT=512 (round-8 proportions, half tile) -> 2 blocks/CU, no spill ----
__global__ __launch_bounds__(512) void moe_fused_kernel(
    const ushort* __restrict__ xb, const ushort* __restrict__ w1t,
    const ushort* __restrict__ w2t, const ushort* __restrict__ w3t,
    const float* __restrict__ eb1, const float* __restrict__ eb2,
    const float* __restrict__ eb3, const float* __restrict__ gatef,
    float* __restrict__ velout) {
  __shared__ __align__(16) ushort smA[64 * 64];     //  8 KB: x K-tile (swizzled)
  __shared__ __align__(16) ushort smB[256 * 64];    // 32 KB: weight K-tile (swizzled)
  __shared__ __align__(16) ushort hbuf[64 * 256];   // 32 KB: h tile (swizzled)
  __shared__ float sGate[64 * 8];                   //  2 KB
  // total 75,776 B -> 2 blocks/CU x 8 waves = 16 waves/CU (4/SIMD)

  const int tid = threadIdx.x;
  const int row0 = blockIdx.x * 64;
  const int l = tid & 63;
  const int w = tid >> 6;     // 8 waves: 2(M) x 4(N), wave tile 32 rows x 64 cols
  const int wm = w >> 2;
  const int wn = w & 3;
  const int lr = l & 15;
  const int lk = (l >> 4) * 8;
  const int q4 = (l >> 4) * 4;

  if (tid < 512) sGate[tid] = gatef[(size_t)row0 * 8 + tid];

  const ushort* xrow = xb + (size_t)row0 * 640;
  f32x4 vacc[2][4] = {};
  __syncthreads();

  for (int e = 0; e < 8; ++e) {
    const ushort* W1 = w1t + (size_t)e * (256 * 640);
    const ushort* W2 = w2t + (size_t)e * (256 * 256);
    const ushort* W3 = w3t + (size_t)e * (256 * 256);

    // ---- stage 1: h1 = silu(x @ W1 + b1), K=640 ----
    f32x4 acc[2][4] = {};
    for (int kt = 0; kt < 640; kt += 64) {
      stageA64_512s(xrow, 640, kt, smA, tid);
      stageB256_512s(W1, 640, kt, smB, tid);
      __syncthreads();
      #pragma unroll
      for (int kk = 0; kk < 2; ++kk) {
        int kb = kk * 32 + lk;
        bf16x8 av[2], bv[4];
        #pragma unroll
        for (int mf = 0; mf < 2; ++mf)
          av[mf] = *(const bf16x8*)&smA[kswz(wm * 32 + mf * 16 + lr, kb)];
        #pragma unroll
        for (int nf = 0; nf < 4; ++nf)
          bv[nf] = *(const bf16x8*)&smB[kswz(wn * 64 + nf * 16 + lr, kb)];
        #pragma unroll
        for (int mf = 0; mf < 2; ++mf)
          #pragma unroll
          for (int nf = 0; nf < 4; ++nf)
            acc[mf][nf] = __builtin_amdgcn_mfma_f32_16x16x32_bf16(av[mf], bv[nf], acc[mf][nf], 0, 0, 0);
      }
      __syncthreads();
    }
    // epilogue 1 -> hbuf (swizzled)
    #pragma unroll
    for (int nf = 0; nf < 4; ++nf) {
      int cc = wn * 64 + nf * 16 + lr;
      float b1v = eb1[e * 256 + cc];
      #pragma unroll
      for (int mf = 0; mf < 2; ++mf)
        #pragma unroll
        for (int rg = 0; rg < 4; ++rg) {
          int rr = wm * 32 + mf * 16 + q4 + rg;
          hbuf[hswz(rr, cc)] = f2bf(silu_f(acc[mf][nf][rg] + b1v));
        }
    }
    __syncthreads();

    // ---- stage 2: h2g = gate * silu(h1 @ W2 + b2), K=256 ----
    #pragma unroll
    for (int mf = 0; mf < 2; ++mf)
      #pragma unroll
      for (int nf = 0; nf < 4; ++nf)
        acc[mf][nf] = (f32x4){0.f, 0.f, 0.f, 0.f};
    for (int kt = 0; kt < 256; kt += 64) {
      stageB256_512s(W2, 256, kt, smB, tid);
      __syncthreads();
      #pragma unroll
      for (int kk = 0; kk < 2; ++kk) {
        int kbl = kk * 32 + lk;
        int kbh = kt + kbl;
        bf16x8 av[2], bv[4];
        #pragma unroll
        for (int mf = 0; mf < 2; ++mf)
          av[mf] = *(const bf16x8*)&hbuf[hswz(wm * 32 + mf * 16 + lr, kbh)];
        #pragma unroll
        for (int nf = 0; nf < 4; ++nf)
          bv[nf] = *(const bf16x8*)&smB[kswz(wn * 64 + nf * 16 + lr, kbl)];
        #pragma unroll
        for (int mf = 0; mf < 2; ++mf)
          #pragma unroll
          for (int nf = 0; nf < 4; ++nf)
            acc[mf][nf] = __builtin_amdgcn_mfma_f32_16x16x32_bf16(av[mf], bv[nf], acc[mf][nf], 0, 0, 0);
      }
      __syncthreads();
    }
    // epilogue 2 -> hbuf (gate folded in; reads drained by trailing barrier)
    #pragma unroll
    for (int nf = 0; nf < 4; ++nf) {
      int cc = wn * 64 + nf * 16 + lr;
      float b2v = eb2[e * 256 + cc];
      #pragma unroll
      for (int mf = 0; mf < 2; ++mf)
        #pragma unroll
        for (int rg = 0; rg < 4; ++rg) {
          int rr = wm * 32 + mf * 16 + q4 + rg;
          float gv = sGate[rr * 8 + e];
          hbuf[hswz(rr, cc)] = f2bf(silu_f(acc[mf][nf][rg] + b2v) * gv);
        }
    }
    __syncthreads();

    // ---- stage 3: vacc += h2g @ W3, K=256 ----
    for (int kt = 0; kt < 256; kt += 64) {
      stageB256_512s(W3, 256, kt, smB, tid);
      __syncthreads();
      #pragma unroll
      for (int kk = 0; kk < 2; ++kk) {
        int kbl = kk * 32 + lk;
        int kbh = kt + kbl;
        bf16x8 av[2], bv[4];
        #pragma unroll
        for (int mf = 0; mf < 2; ++mf)
          av[mf] = *(const bf16x8*)&hbuf[hswz(wm * 32 + mf * 16 + lr, kbh)];
        #pragma unroll
        for (int nf = 0; nf < 4; ++nf)
          bv[nf] = *(const bf16x8*)&smB[kswz(wn * 64 + nf * 16 + lr, kbl)];
        #pragma unroll
        for (int mf = 0; mf < 2; ++mf)
          #pragma unroll
          for (int nf = 0; nf < 4; ++nf)
            vacc[mf][nf] = __builtin_amdgcn_mfma_f32_16x16x32_bf16(av[mf], bv[nf], vacc[mf][nf], 0, 0, 0);
      }
      __syncthreads();
    }
  }

  // stage eb3 into smA's space (free now; trailing barrier above drained K-loop)
  float* eL = (float*)smA;   // 2048 f32 = 8 KB = smA exactly
  for (int i = tid; i < 2048; i += 512) eL[i] = eb3[i];
  __syncthreads();
  #pragma unroll
  for (int mf = 0; mf < 2; ++mf)
    #pragma unroll
    for (int rg = 0; rg < 4; ++rg) {
      int rr = wm * 32 + mf * 16 + q4 + rg;
      const float* gp = &sGate[rr * 8];
      #pragma unroll
      for (int nf = 0; nf < 4; ++nf) {
        int cc = wn * 64 + nf * 16 + lr;
        float bsum = 0.f;
        #pragma unroll
        for (int ee = 0; ee < 8; ++ee) bsum += gp[ee] * eL[ee * 256 + cc];
        velout[(size_t)(row0 + rr) * D_EMBED + cc] = vacc[mf][nf][rg] + bsum;
      }
    }
}

extern "C" void kernel_launch(void* const* d_in, const int* in_sizes, int n_in,
                              void* d_out, int out_size, void* d_ws, size_t ws_size,
                              hipStream_t stream) {
  const float* zt   = (const float*)d_in[0];
  const float* tin  = (const float*)d_in[1];
  const float* cond = (const float*)d_in[2];
  const float* tW1  = (const float*)d_in[3];
  const float* tb1  = (const float*)d_in[4];
  const float* tW2  = (const float*)d_in[5];
  const float* tb2  = (const float*)d_in[6];
  const float* eW1  = (const float*)d_in[7];
  const float* eb1  = (const float*)d_in[8];
  const float* eW2  = (const float*)d_in[9];
  const float* eb2  = (const float*)d_in[10];
  const float* eW3  = (const float*)d_in[11];
  const float* eb3  = (const float*)d_in[12];
  const float* rW1  = (const float*)d_in[13];
  const float* rb1  = (const float*)d_in[14];
  const float* rW2  = (const float*)d_in[15];
  const float* rb2  = (const float*)d_in[16];

  char* wp = (char*)d_ws;
  ushort* xb    = (ushort*)wp; wp += (size_t)NB_ROWS * D_IN * 2;        // 80 MiB
  float*  gatef = (float*)wp;  wp += (size_t)NB_ROWS * 8 * 4;           // 2 MiB
  ushort* w1t   = (ushort*)wp; wp += (size_t)N_EXP * D_HID * D_IN * 2;
  ushort* w2t   = (ushort*)wp; wp += (size_t)N_EXP * D_HID * D_HID * 2;
  ushort* w3t   = (ushort*)wp; wp += (size_t)N_EXP * D_HID * D_EMBED * 2;
  ushort* rw1t  = (ushort*)wp; wp += (size_t)D_RHID * D_IN * 2;
  ushort* tw1t  = (ushort*)wp; wp += (size_t)128 * 128 * 2;
  ushort* tw2t  = (ushort*)wp; wp += (size_t)128 * 128 * 2;
  // total ~87 MiB (proven safe)

  // FLOAT32 outputs (reference returns jnp.float32)
  float* velout  = (float*)d_out;
  float* gateout = velout + (size_t)NB_ROWS * D_EMBED;

  // weight prep
  {
    int tot;
    tot = 128 * 128;
    prep_transpose<<<(tot + 255) / 256, 256, 0, stream>>>(tW1, tw1t, 128, 128, tot);
    prep_transpose<<<(tot + 255) / 256, 256, 0, stream>>>(tW2, tw2t, 128, 128, tot);
    tot = D_IN * D_RHID;
    prep_transpose<<<(tot + 255) / 256, 256, 0, stream>>>(rW1, rw1t, D_IN, D_RHID, tot);
    tot = N_EXP * D_IN * D_HID;
    prep_transpose<<<(tot + 255) / 256, 256, 0, stream>>>(eW1, w1t, D_IN, D_HID, tot);
    tot = N_EXP * D_HID * D_HID;
    prep_transpose<<<(tot + 255) / 256, 256, 0, stream>>>(eW2, w2t, D_HID, D_HID, tot);
    tot = N_EXP * D_HID * D_EMBED;
    prep_transpose<<<(tot + 255) / 256, 256, 0, stream>>>(eW3, w3t, D_HID, D_EMBED, tot);
  }

  time_x_kernel<<<512, 512, 0, stream>>>(zt, tin, cond, tw1t, tw2t, tb1, tb2, xb);
  router_kernel<<<512, 256, 0, stream>>>(xb, rw1t, rb1, rW2, rb2, gatef, gateout);
  moe_fused_kernel<<<1024, 512, 0, stream>>>(xb, w1t, w2t, w3t, eb1, eb2, eb3, gatef, velout);
}